// Round 2
// baseline (437.295 us; speedup 1.0000x reference)
//
#include <hip/hip_runtime.h>
#include <math.h>

#define IMG_H 512
#define IMG_W 512
#define NPLANES 48            // 16 * 3
#define RAD 5
#define TAPS 11
#define CHUNK 33              // multiple of 11 -> static ring phase after unroll
#define TILE_X 256
#define ROWBUF 272            // 266 used, padded

struct GaussW { float w[TAPS]; };

__global__ __launch_bounds__(256, 6)   // 6 blocks/CU = 24 waves/CU
void ssim_main(const float* __restrict__ img1, const float* __restrict__ img2,
               double* __restrict__ sum_ws, GaussW gw) {
    __shared__ float2 srow[2][ROWBUF];   // (x1, x2) row, double-buffered
    __shared__ float wsum[4];

    const int tid = threadIdx.x;
    const int cx0 = blockIdx.x * TILE_X;
    const int y0  = blockIdx.y * CHUNK;
    const size_t pbase = (size_t)blockIdx.z * (IMG_H * IMG_W);
    const float* p1 = img1 + pbase;
    const float* p2 = img2 + pbase;

    // register ring: horizontal conv results for the 5 quantities, 11 rows deep
    float r1[TAPS], r2[TAPS], r11[TAPS], r22[TAPS], r12[TAPS];

    // prefetch registers for the next row (main cols + 10-col tail)
    float pa, pb, pta, ptb;

    auto load_regs = [&](int r) {
        pa = pb = pta = ptb = 0.f;
        if (r >= 0 && r < IMG_H) {
            const float* row1 = p1 + (size_t)r * IMG_W;
            const float* row2 = p2 + (size_t)r * IMG_W;
            int col = cx0 - RAD + tid;
            if (col >= 0 && col < IMG_W) { pa = row1[col]; pb = row2[col]; }
            if (tid < 2 * RAD) {                 // tail columns 256..265
                int c2 = cx0 - RAD + 256 + tid;
                if (c2 >= 0 && c2 < IMG_W) { pta = row1[c2]; ptb = row2[c2]; }
            }
        }
    };

    auto store_lds = [&](int p) {
        srow[p][tid] = make_float2(pa, pb);
        if (tid < 2 * RAD) srow[p][256 + tid] = make_float2(pta, ptb);
    };

    auto hconv = [&](int r, int p, float& o1, float& o2, float& o11, float& o22, float& o12) {
        float a1 = 0.f, a2 = 0.f, a11 = 0.f, a22 = 0.f, a12 = 0.f;
        if (r >= 0 && r < IMG_H) {   // wave-uniform branch: skip zero-padded rows
            #pragma unroll
            for (int d = 0; d < TAPS; ++d) {
                float2 v = srow[p][tid + d];
                float wv = gw.w[d];
                a1  = fmaf(wv, v.x, a1);
                a2  = fmaf(wv, v.y, a2);
                a11 = fmaf(wv, v.x * v.x, a11);
                a22 = fmaf(wv, v.y * v.y, a22);
                a12 = fmaf(wv, v.x * v.y, a12);
            }
        }
        o1 = a1; o2 = a2; o11 = a11; o22 = a22; o12 = a12;
    };

    // ---- prologue: h-rows 0..9 (global rows y0-5 .. y0+4) -> ring slots 0..9
    load_regs(y0 - RAD);
    #pragma unroll
    for (int k = 0; k < TAPS - 1; ++k) {
        const int r = y0 - RAD + k;
        store_lds(k & 1);
        __syncthreads();
        load_regs(r + 1);                         // prefetch next row (in flight during hconv)
        hconv(r, k & 1, r1[k], r2[k], r11[k], r22[k], r12[k]);
    }

    const float C1v = 0.0001f;  // 0.01^2
    const float C2v = 0.0009f;  // 0.03^2
    float acc = 0.f;

    // ---- main: CHUNK output rows, unrolled by 11 so ring indices are static
    for (int kk = 0; kk < CHUNK; kk += TAPS) {
        #pragma unroll
        for (int j = 0; j < TAPS; ++j) {
            const int lr = (TAPS - 1) + kk + j;   // local h-row index
            const int r  = y0 - RAD + lr;         // global input row
            const int p  = lr & 1;
            store_lds(p);                         // consume prefetched row r
            __syncthreads();
            load_regs(r + 1);                     // issue loads for row r+1 NOW
            // hconv row r into ring slot (10+j)%11 (static after unroll)
            hconv(r, p, r1[(j + 10) % TAPS], r2[(j + 10) % TAPS],
                  r11[(j + 10) % TAPS], r22[(j + 10) % TAPS], r12[(j + 10) % TAPS]);

            const int y = y0 + kk + j;            // output row
            if (y < IMG_H) {
                float mu1 = 0.f, mu2 = 0.f, s11 = 0.f, s22 = 0.f, s12 = 0.f;
                #pragma unroll
                for (int t = 0; t < TAPS; ++t) {
                    const int s = (j + t) % TAPS; // static after unroll
                    float wv = gw.w[t];
                    mu1 = fmaf(wv, r1[s], mu1);
                    mu2 = fmaf(wv, r2[s], mu2);
                    s11 = fmaf(wv, r11[s], s11);
                    s22 = fmaf(wv, r22[s], s22);
                    s12 = fmaf(wv, r12[s], s12);
                }
                float mu1sq = mu1 * mu1, mu2sq = mu2 * mu2, mu12 = mu1 * mu2;
                float sg1 = s11 - mu1sq, sg2 = s22 - mu2sq, sg12 = s12 - mu12;
                float num = (2.f * mu12 + C1v) * (2.f * sg12 + C2v);
                float den = (mu1sq + mu2sq + C1v) * (sg1 + sg2 + C2v);
                acc += num * __builtin_amdgcn_rcpf(den);
            }
        }
    }

    // wave (64-lane) shuffle reduce, then block partials, then one atomic
    #pragma unroll
    for (int off = 32; off > 0; off >>= 1) acc += __shfl_down(acc, off, 64);
    if ((tid & 63) == 0) wsum[tid >> 6] = acc;
    __syncthreads();
    if (tid == 0) {
        double s = (double)wsum[0] + (double)wsum[1] + (double)wsum[2] + (double)wsum[3];
        atomicAdd(sum_ws, s);
    }
}

__global__ void ssim_finalize(const double* __restrict__ sum_ws, float* __restrict__ out) {
    out[0] = (float)(sum_ws[0] * (1.0 / (double)(16.0 * 3.0 * 512.0 * 512.0)));
}

extern "C" void kernel_launch(void* const* d_in, const int* in_sizes, int n_in,
                              void* d_out, int out_size, void* d_ws, size_t ws_size,
                              hipStream_t stream) {
    const float* img1 = (const float*)d_in[0];
    const float* img2 = (const float*)d_in[1];
    float* out = (float*)d_out;
    double* ws = (double*)d_ws;

    // d_ws is poisoned 0xAA before every launch — zero the accumulator (async, capture-safe)
    hipMemsetAsync(ws, 0, sizeof(double), stream);

    // Gaussian weights computed on host in double, passed via kernarg (SGPRs)
    GaussW gw;
    double g[TAPS], s = 0.0;
    for (int i = 0; i < TAPS; ++i) {
        double x = (double)(i - TAPS / 2);
        g[i] = exp(-(x * x) / (2.0 * 1.5 * 1.5));
        s += g[i];
    }
    for (int i = 0; i < TAPS; ++i) gw.w[i] = (float)(g[i] / s);

    // 2 x 16 x 48 = 1536 blocks = 6 blocks/CU
    dim3 grid(IMG_W / TILE_X, (IMG_H + CHUNK - 1) / CHUNK, NPLANES);
    ssim_main<<<grid, 256, 0, stream>>>(img1, img2, ws, gw);
    ssim_finalize<<<1, 1, 0, stream>>>(ws, out);
}

// Round 3
// 205.006 us; speedup vs baseline: 2.1331x; 2.1331x over previous
//
#include <hip/hip_runtime.h>
#include <math.h>

#define IMG_H 512
#define IMG_W 512
#define NPLANES 48            // 16 * 3
#define RAD 5
#define TAPS 11
#define CHUNK 33              // multiple of 11 -> static ring phase after unroll
#define TILE_X 256
#define ROWBUF 272            // 266 used, padded

struct GaussW { float w[TAPS]; };

// NOTE: min-waves arg MUST stay low. (256,6) caps the allocator at ~40 VGPR and
// the 55-float ring spills to scratch: R2 measured WRITE_SIZE 24KB->291MB,
// dur 105->350us. (256,4) gives 128-VGPR budget; body uses ~56, no spill.
__global__ __launch_bounds__(256, 4)
void ssim_main(const float* __restrict__ img1, const float* __restrict__ img2,
               double* __restrict__ sum_ws, GaussW gw) {
    __shared__ float2 srow[2][ROWBUF];   // (x1, x2) interleaved row, double-buffered
    __shared__ float wsum[4];

    const int tid = threadIdx.x;
    const int cx0 = blockIdx.x * TILE_X;
    const int y0  = blockIdx.y * CHUNK;
    const size_t pbase = (size_t)blockIdx.z * (IMG_H * IMG_W);
    const float* p1 = img1 + pbase;
    const float* p2 = img2 + pbase;

    // register ring: horizontal conv results for the 5 quantities, 11 rows deep
    float r1[TAPS], r2[TAPS], r11[TAPS], r22[TAPS], r12[TAPS];

    auto stage = [&](int r, int p) {
        if (r >= 0 && r < IMG_H) {
            const float* row1 = p1 + (size_t)r * IMG_W;
            const float* row2 = p2 + (size_t)r * IMG_W;
            int col = cx0 - RAD + tid;
            float a = 0.f, b = 0.f;
            if (col >= 0 && col < IMG_W) { a = row1[col]; b = row2[col]; }
            srow[p][tid] = make_float2(a, b);
            if (tid < 2 * RAD) {                 // tail columns 256..265
                int i = 256 + tid;
                int c2 = cx0 - RAD + i;
                float a2 = 0.f, b2 = 0.f;
                if (c2 >= 0 && c2 < IMG_W) { a2 = row1[c2]; b2 = row2[c2]; }
                srow[p][i] = make_float2(a2, b2);
            }
        }
    };

    auto hconv = [&](int r, int p, float& o1, float& o2, float& o11, float& o22, float& o12) {
        float a1 = 0.f, a2 = 0.f, a11 = 0.f, a22 = 0.f, a12 = 0.f;
        if (r >= 0 && r < IMG_H) {   // wave-uniform branch: zero-padded rows contribute zero
            #pragma unroll
            for (int d = 0; d < TAPS; ++d) {
                float2 v = srow[p][tid + d];
                float wv = gw.w[d];
                a1  = fmaf(wv, v.x, a1);
                a2  = fmaf(wv, v.y, a2);
                a11 = fmaf(wv, v.x * v.x, a11);
                a22 = fmaf(wv, v.y * v.y, a22);
                a12 = fmaf(wv, v.x * v.y, a12);
            }
        }
        o1 = a1; o2 = a2; o11 = a11; o22 = a22; o12 = a12;
    };

    // ---- prologue: h-rows 0..9 (global rows y0-5 .. y0+4) -> ring slots 0..9
    #pragma unroll
    for (int k = 0; k < TAPS - 1; ++k) {
        const int r = y0 - RAD + k;
        stage(r, k & 1);
        __syncthreads();
        hconv(r, k & 1, r1[k], r2[k], r11[k], r22[k], r12[k]);
    }

    const float C1v = 0.0001f;  // 0.01^2
    const float C2v = 0.0009f;  // 0.03^2
    float acc = 0.f;

    // ---- main: CHUNK output rows, unrolled by 11 so ring indices are static
    for (int kk = 0; kk < CHUNK; kk += TAPS) {
        #pragma unroll
        for (int j = 0; j < TAPS; ++j) {
            const int lr = (TAPS - 1) + kk + j;   // local h-row index
            const int r  = y0 - RAD + lr;         // global input row
            const int p  = lr & 1;
            stage(r, p);
            __syncthreads();
            // hconv row r into ring slot (10+j)%11 (static after unroll)
            hconv(r, p, r1[(j + 10) % TAPS], r2[(j + 10) % TAPS],
                  r11[(j + 10) % TAPS], r22[(j + 10) % TAPS], r12[(j + 10) % TAPS]);

            const int y = y0 + kk + j;            // output row
            if (y < IMG_H) {
                float mu1 = 0.f, mu2 = 0.f, s11 = 0.f, s22 = 0.f, s12 = 0.f;
                #pragma unroll
                for (int t = 0; t < TAPS; ++t) {
                    const int s = (j + t) % TAPS; // static after unroll
                    float wv = gw.w[t];
                    mu1 = fmaf(wv, r1[s], mu1);
                    mu2 = fmaf(wv, r2[s], mu2);
                    s11 = fmaf(wv, r11[s], s11);
                    s22 = fmaf(wv, r22[s], s22);
                    s12 = fmaf(wv, r12[s], s12);
                }
                float mu1sq = mu1 * mu1, mu2sq = mu2 * mu2, mu12 = mu1 * mu2;
                float sg1 = s11 - mu1sq, sg2 = s22 - mu2sq, sg12 = s12 - mu12;
                float num = (2.f * mu12 + C1v) * (2.f * sg12 + C2v);
                float den = (mu1sq + mu2sq + C1v) * (sg1 + sg2 + C2v);
                acc += num * __builtin_amdgcn_rcpf(den);
            }
        }
    }

    // wave (64-lane) shuffle reduce, then block partials, then one atomic
    #pragma unroll
    for (int off = 32; off > 0; off >>= 1) acc += __shfl_down(acc, off, 64);
    if ((tid & 63) == 0) wsum[tid >> 6] = acc;
    __syncthreads();
    if (tid == 0) {
        double s = (double)wsum[0] + (double)wsum[1] + (double)wsum[2] + (double)wsum[3];
        atomicAdd(sum_ws, s);
    }
}

__global__ void ssim_finalize(const double* __restrict__ sum_ws, float* __restrict__ out) {
    out[0] = (float)(sum_ws[0] * (1.0 / (double)(16.0 * 3.0 * 512.0 * 512.0)));
}

extern "C" void kernel_launch(void* const* d_in, const int* in_sizes, int n_in,
                              void* d_out, int out_size, void* d_ws, size_t ws_size,
                              hipStream_t stream) {
    const float* img1 = (const float*)d_in[0];
    const float* img2 = (const float*)d_in[1];
    float* out = (float*)d_out;
    double* ws = (double*)d_ws;

    // d_ws is poisoned 0xAA before every launch — zero the accumulator (async, capture-safe)
    hipMemsetAsync(ws, 0, sizeof(double), stream);

    // Gaussian weights computed on host in double, passed via kernarg (SGPRs)
    GaussW gw;
    double g[TAPS], s = 0.0;
    for (int i = 0; i < TAPS; ++i) {
        double x = (double)(i - TAPS / 2);
        g[i] = exp(-(x * x) / (2.0 * 1.5 * 1.5));
        s += g[i];
    }
    for (int i = 0; i < TAPS; ++i) gw.w[i] = (float)(g[i] / s);

    // 2 x 16 x 48 = 1536 blocks = 6 blocks/CU resident (24 waves/CU, 75% occ)
    dim3 grid(IMG_W / TILE_X, (IMG_H + CHUNK - 1) / CHUNK, NPLANES);
    ssim_main<<<grid, 256, 0, stream>>>(img1, img2, ws, gw);
    ssim_finalize<<<1, 1, 0, stream>>>(ws, out);
}

// Round 5
// 162.246 us; speedup vs baseline: 2.6953x; 1.2636x over previous
//
#include <hip/hip_runtime.h>
#include <math.h>

#define IMG_H 512
#define IMG_W 512
#define NPLANES 48            // 16 * 3
#define RAD 5
#define TAPS 11
#define CHUNK 33              // multiple of 11 -> static ring phase after unroll
#define STRIP 64              // columns per wave (one autonomous wave per strip)
#define SBUF 80               // 74 used (64 + 2*RAD), padded

// Compiler-only fence: cross-lane LDS dependence (lane i reads what lane j
// wrote) is INVISIBLE to LLVM alias analysis — buf[lane] vs buf[lane+d] (d>=1
// constant) are provably distinct per-thread, so without a fence the compiler
// may reorder ds_read above ds_write (R4 failed correctness exactly this way;
// R2/R3 were saved only by __syncthreads' implicit compiler fence).
// HW needs nothing: wave has one PC and same-wave DS ops complete in order.
#define WAVE_FENCE_WAR()  __asm__ __volatile__("" ::: "memory")
#define WAVE_FENCE_RAW()  __asm__ __volatile__("s_waitcnt lgkmcnt(0)" ::: "memory")

struct GaussW { float w[TAPS]; };

// Structure notes (evidence-driven):
//  - R2: __launch_bounds__(256,6) capped VGPR at 40 -> 55-float ring spilled,
//    WRITE_SIZE 24KB->291MB, 350us. Keep (256,4) = 128-VGPR budget, no spill.
//  - R3: block-wide row loop with __syncthreads per staged row is lockstep:
//    dur tracked total staged rows exactly, VALUBusy 42%. Fix: one wave per
//    64-col strip, private LDS buffer, no block barriers in the hot loop.
__global__ __launch_bounds__(256, 4)
void ssim_main(const float* __restrict__ img1, const float* __restrict__ img2,
               double* __restrict__ sum_ws, GaussW gw) {
    __shared__ float2 srow[4][SBUF];   // one private row buffer per wave
    __shared__ float wsum[4];

    const int tid  = threadIdx.x;
    const int wid  = tid >> 6;         // wave id 0..3
    const int lane = tid & 63;
    const int c0   = blockIdx.x * (4 * STRIP) + wid * STRIP;  // strip base col
    const int y0   = blockIdx.y * CHUNK;
    const size_t pbase = (size_t)blockIdx.z * (IMG_H * IMG_W);
    const float* p1 = img1 + pbase;
    const float* p2 = img2 + pbase;
    float2* buf = srow[wid];

    // register ring: horizontal conv results for the 5 quantities, 11 rows deep
    float r1[TAPS], r2[TAPS], r11[TAPS], r22[TAPS], r12[TAPS];

    // prefetch registers for the next row (main col + 10-col tail)
    float pa, pb, pta, ptb;

    auto load_regs = [&](int r) {
        pa = pb = pta = ptb = 0.f;
        if (r >= 0 && r < IMG_H) {     // wave-uniform
            const float* row1 = p1 + (size_t)r * IMG_W;
            const float* row2 = p2 + (size_t)r * IMG_W;
            int col = c0 - RAD + lane;              // buf idx = lane
            if (col >= 0 && col < IMG_W) { pa = row1[col]; pb = row2[col]; }
            if (lane < 2 * RAD) {                   // buf idx = 64+lane
                int c2 = c0 + STRIP - RAD + lane;   // cols c0+59..c0+68
                if (c2 < IMG_W) { pta = row1[c2]; ptb = row2[c2]; }
            }
        }
    };

    auto store_lds = [&]() {
        WAVE_FENCE_WAR();              // don't sink this write above prior reads
        buf[lane] = make_float2(pa, pb);
        if (lane < 2 * RAD) buf[STRIP + lane] = make_float2(pta, ptb);
        WAVE_FENCE_RAW();              // don't hoist following reads above it
    };

    auto hconv = [&](int r, float& o1, float& o2, float& o11, float& o22, float& o12) {
        float a1 = 0.f, a2 = 0.f, a11 = 0.f, a22 = 0.f, a12 = 0.f;
        if (r >= 0 && r < IMG_H) {     // wave-uniform: padded rows contribute zero
            #pragma unroll
            for (int d = 0; d < TAPS; ++d) {
                float2 v = buf[lane + d];
                float wv = gw.w[d];
                a1  = fmaf(wv, v.x, a1);
                a2  = fmaf(wv, v.y, a2);
                a11 = fmaf(wv, v.x * v.x, a11);
                a22 = fmaf(wv, v.y * v.y, a22);
                a12 = fmaf(wv, v.x * v.y, a12);
            }
        }
        o1 = a1; o2 = a2; o11 = a11; o22 = a22; o12 = a12;
    };

    // ---- prologue: h-rows 0..9 (global rows y0-5 .. y0+4) -> ring slots 0..9
    load_regs(y0 - RAD);
    #pragma unroll
    for (int k = 0; k < TAPS - 1; ++k) {
        const int r = y0 - RAD + k;
        store_lds();
        load_regs(r + 1);              // next row's loads in flight during hconv
        hconv(r, r1[k], r2[k], r11[k], r22[k], r12[k]);
    }

    const float C1v = 0.0001f;  // 0.01^2
    const float C2v = 0.0009f;  // 0.03^2
    float acc = 0.f;

    // ---- main: CHUNK output rows, unrolled by 11 so ring indices are static
    for (int kk = 0; kk < CHUNK; kk += TAPS) {
        #pragma unroll
        for (int j = 0; j < TAPS; ++j) {
            const int r = y0 - RAD + (TAPS - 1) + kk + j;  // global input row
            store_lds();               // publish prefetched row r
            load_regs(r + 1);          // issue loads for row r+1 NOW
            hconv(r, r1[(j + 10) % TAPS], r2[(j + 10) % TAPS],
                  r11[(j + 10) % TAPS], r22[(j + 10) % TAPS], r12[(j + 10) % TAPS]);

            const int y = y0 + kk + j; // output row
            if (y < IMG_H) {
                float mu1 = 0.f, mu2 = 0.f, s11 = 0.f, s22 = 0.f, s12 = 0.f;
                #pragma unroll
                for (int t = 0; t < TAPS; ++t) {
                    const int s = (j + t) % TAPS;  // static after unroll
                    float wv = gw.w[t];
                    mu1 = fmaf(wv, r1[s], mu1);
                    mu2 = fmaf(wv, r2[s], mu2);
                    s11 = fmaf(wv, r11[s], s11);
                    s22 = fmaf(wv, r22[s], s22);
                    s12 = fmaf(wv, r12[s], s12);
                }
                float mu1sq = mu1 * mu1, mu2sq = mu2 * mu2, mu12 = mu1 * mu2;
                float sg1 = s11 - mu1sq, sg2 = s22 - mu2sq, sg12 = s12 - mu12;
                float num = (2.f * mu12 + C1v) * (2.f * sg12 + C2v);
                float den = (mu1sq + mu2sq + C1v) * (sg1 + sg2 + C2v);
                acc += num * __builtin_amdgcn_rcpf(den);
            }
        }
    }

    // wave (64-lane) shuffle reduce -> block partials -> one atomic per block
    #pragma unroll
    for (int off = 32; off > 0; off >>= 1) acc += __shfl_down(acc, off, 64);
    if (lane == 0) wsum[wid] = acc;
    __syncthreads();                   // only block barrier in the kernel
    if (tid == 0) {
        double s = (double)wsum[0] + (double)wsum[1] + (double)wsum[2] + (double)wsum[3];
        atomicAdd(sum_ws, s);
    }
}

__global__ void ssim_finalize(const double* __restrict__ sum_ws, float* __restrict__ out) {
    out[0] = (float)(sum_ws[0] * (1.0 / (double)(16.0 * 3.0 * 512.0 * 512.0)));
}

extern "C" void kernel_launch(void* const* d_in, const int* in_sizes, int n_in,
                              void* d_out, int out_size, void* d_ws, size_t ws_size,
                              hipStream_t stream) {
    const float* img1 = (const float*)d_in[0];
    const float* img2 = (const float*)d_in[1];
    float* out = (float*)d_out;
    double* ws = (double*)d_ws;

    // d_ws is poisoned 0xAA before every launch — zero the accumulator (async, capture-safe)
    hipMemsetAsync(ws, 0, sizeof(double), stream);

    // Gaussian weights computed on host in double, passed via kernarg (SGPRs)
    GaussW gw;
    double g[TAPS], s = 0.0;
    for (int i = 0; i < TAPS; ++i) {
        double x = (double)(i - TAPS / 2);
        g[i] = exp(-(x * x) / (2.0 * 1.5 * 1.5));
        s += g[i];
    }
    for (int i = 0; i < TAPS; ++i) gw.w[i] = (float)(g[i] / s);

    // 2 x 16 x 48 = 1536 blocks; each block = 4 autonomous 64-col wave strips
    dim3 grid(IMG_W / (4 * STRIP), (IMG_H + CHUNK - 1) / CHUNK, NPLANES);
    ssim_main<<<grid, 256, 0, stream>>>(img1, img2, ws, gw);
    ssim_finalize<<<1, 1, 0, stream>>>(ws, out);
}

// Round 6
// 152.870 us; speedup vs baseline: 2.8606x; 1.0613x over previous
//
#include <hip/hip_runtime.h>
#include <math.h>

#define IMG_H 512
#define IMG_W 512
#define NPLANES 48            // 16 * 3
#define RAD 5
#define TAPS 11
#define CHUNK 33              // multiple of 11 -> static ring phase after unroll
#define STRIP 64              // columns per wave (one autonomous wave per strip)
#define SBUF 80               // 74 used (64 + 2*RAD), padded

typedef float v2f __attribute__((ext_vector_type(2)));

// Compiler-only fence: cross-lane LDS dependence (lane i reads what lane j
// wrote) is INVISIBLE to LLVM alias analysis — R4 failed correctness exactly
// this way (reads hoisted above writes once __syncthreads was removed).
// HW needs nothing: wave has one PC and same-wave DS ops complete in order.
#define WAVE_FENCE_WAR()  __asm__ __volatile__("" ::: "memory")
#define WAVE_FENCE_RAW()  __asm__ __volatile__("s_waitcnt lgkmcnt(0)" ::: "memory")

struct GaussW { float w[TAPS]; };

// Structure notes (evidence-driven):
//  - R2: __launch_bounds__(256,6) capped VGPR at 40 -> 55-float ring spilled,
//    WRITE_SIZE 24KB->291MB, 350us. Keep (256,4) = 128-VGPR budget.
//  - R3: block-wide __syncthreads per staged row is lockstep (VALUBusy 42%).
//    R5: one wave per 64-col strip, no block barriers -> 77us, VALUBusy 70%,
//    VALU-issue-bound. R6: packed fp32 (v_pk_fma) to cut VALU inst/px ~35%.
__global__ __launch_bounds__(256, 4)
void ssim_main(const float* __restrict__ img1, const float* __restrict__ img2,
               double* __restrict__ sum_ws, GaussW gw) {
    __shared__ float2 srow[4][SBUF];   // one private (a,b) row buffer per wave
    __shared__ float wsum[4];

    const int tid  = threadIdx.x;
    const int wid  = tid >> 6;         // wave id 0..3
    const int lane = tid & 63;
    const int c0   = blockIdx.x * (4 * STRIP) + wid * STRIP;  // strip base col
    const int y0   = blockIdx.y * CHUNK;
    const size_t pbase = (size_t)blockIdx.z * (IMG_H * IMG_W);
    const float* p1 = img1 + pbase;
    const float* p2 = img2 + pbase;
    float2* buf = srow[wid];

    // register ring, 11 rows deep:
    //   rab = (conv_h(a), conv_h(b))   packed
    //   rsq = (conv_h(a^2), conv_h(b^2)) packed
    //   rx  = conv_h(a*b)              scalar
    v2f rab[TAPS], rsq[TAPS];
    float rx[TAPS];

    // prefetch registers for the next row (main col + 10-col tail)
    float pa, pb, pta, ptb;

    auto load_regs = [&](int r) {
        pa = pb = pta = ptb = 0.f;
        if (r >= 0 && r < IMG_H) {     // wave-uniform
            const float* row1 = p1 + (size_t)r * IMG_W;
            const float* row2 = p2 + (size_t)r * IMG_W;
            int col = c0 - RAD + lane;              // buf idx = lane
            if (col >= 0 && col < IMG_W) { pa = row1[col]; pb = row2[col]; }
            if (lane < 2 * RAD) {                   // buf idx = 64+lane
                int c2 = c0 + STRIP - RAD + lane;   // cols c0+59..c0+68
                if (c2 < IMG_W) { pta = row1[c2]; ptb = row2[c2]; }
            }
        }
    };

    auto store_lds = [&]() {
        WAVE_FENCE_WAR();              // don't sink this write above prior reads
        buf[lane] = make_float2(pa, pb);
        if (lane < 2 * RAD) buf[STRIP + lane] = make_float2(pta, ptb);
        WAVE_FENCE_RAW();              // don't hoist following reads above it
    };

    // packed horizontal conv: per tap 1 pk_mul + 1 mul + 2 pk_fma + 1 fma
    auto hconv = [&](int r, v2f& oab, v2f& osq, float& ox) {
        v2f aab = {0.f, 0.f}, asq = {0.f, 0.f};
        float ax = 0.f;
        if (r >= 0 && r < IMG_H) {     // wave-uniform: padded rows contribute zero
            #pragma unroll
            for (int d = 0; d < TAPS; ++d) {
                v2f v = *(const v2f*)&buf[lane + d];   // (a, b)
                float w = gw.w[d];
                v2f wv = {w, w};
                aab = __builtin_elementwise_fma(wv, v, aab);          // pk_fma
                v2f sq = v * v;                                       // pk_mul
                asq = __builtin_elementwise_fma(wv, sq, asq);         // pk_fma
                ax  = fmaf(w, v.x * v.y, ax);                         // mul+fma
            }
        }
        oab = aab; osq = asq; ox = ax;
    };

    // ---- prologue: h-rows 0..9 (global rows y0-5 .. y0+4) -> ring slots 0..9
    load_regs(y0 - RAD);
    #pragma unroll
    for (int k = 0; k < TAPS - 1; ++k) {
        const int r = y0 - RAD + k;
        store_lds();
        load_regs(r + 1);              // next row's loads in flight during hconv
        hconv(r, rab[k], rsq[k], rx[k]);
    }

    const float C1v = 0.0001f;  // 0.01^2
    const float C2v = 0.0009f;  // 0.03^2
    float acc = 0.f;

    // ---- main: CHUNK output rows, unrolled by 11 so ring indices are static
    for (int kk = 0; kk < CHUNK; kk += TAPS) {
        #pragma unroll
        for (int j = 0; j < TAPS; ++j) {
            const int r = y0 - RAD + (TAPS - 1) + kk + j;  // global input row
            store_lds();               // publish prefetched row r
            load_regs(r + 1);          // issue loads for row r+1 NOW
            hconv(r, rab[(j + 10) % TAPS], rsq[(j + 10) % TAPS], rx[(j + 10) % TAPS]);

            const int y = y0 + kk + j; // output row
            if (y < IMG_H) {
                // packed vertical conv: per tap 2 pk_fma + 1 fma
                v2f mu = {0.f, 0.f}, s2 = {0.f, 0.f};
                float sx = 0.f;
                #pragma unroll
                for (int t = 0; t < TAPS; ++t) {
                    const int s = (j + t) % TAPS;  // static after unroll
                    float w = gw.w[t];
                    v2f wv = {w, w};
                    mu = __builtin_elementwise_fma(wv, rab[s], mu);
                    s2 = __builtin_elementwise_fma(wv, rsq[s], s2);
                    sx = fmaf(w, rx[s], sx);
                }
                float mu1 = mu.x, mu2 = mu.y;
                float mu1sq = mu1 * mu1, mu2sq = mu2 * mu2, mu12 = mu1 * mu2;
                float sg1 = s2.x - mu1sq, sg2 = s2.y - mu2sq, sg12 = sx - mu12;
                float num = (2.f * mu12 + C1v) * (2.f * sg12 + C2v);
                float den = (mu1sq + mu2sq + C1v) * (sg1 + sg2 + C2v);
                acc += num * __builtin_amdgcn_rcpf(den);
            }
        }
    }

    // wave (64-lane) shuffle reduce -> block partials -> one atomic per block
    #pragma unroll
    for (int off = 32; off > 0; off >>= 1) acc += __shfl_down(acc, off, 64);
    if (lane == 0) wsum[wid] = acc;
    __syncthreads();                   // only block barrier in the kernel
    if (tid == 0) {
        double s = (double)wsum[0] + (double)wsum[1] + (double)wsum[2] + (double)wsum[3];
        atomicAdd(sum_ws, s);
    }
}

__global__ void ssim_finalize(const double* __restrict__ sum_ws, float* __restrict__ out) {
    out[0] = (float)(sum_ws[0] * (1.0 / (double)(16.0 * 3.0 * 512.0 * 512.0)));
}

extern "C" void kernel_launch(void* const* d_in, const int* in_sizes, int n_in,
                              void* d_out, int out_size, void* d_ws, size_t ws_size,
                              hipStream_t stream) {
    const float* img1 = (const float*)d_in[0];
    const float* img2 = (const float*)d_in[1];
    float* out = (float*)d_out;
    double* ws = (double*)d_ws;

    // d_ws is poisoned 0xAA before every launch — zero the accumulator (async, capture-safe)
    hipMemsetAsync(ws, 0, sizeof(double), stream);

    // Gaussian weights computed on host in double, passed via kernarg (SGPRs)
    GaussW gw;
    double g[TAPS], s = 0.0;
    for (int i = 0; i < TAPS; ++i) {
        double x = (double)(i - TAPS / 2);
        g[i] = exp(-(x * x) / (2.0 * 1.5 * 1.5));
        s += g[i];
    }
    for (int i = 0; i < TAPS; ++i) gw.w[i] = (float)(g[i] / s);

    // 2 x 16 x 48 = 1536 blocks; each block = 4 autonomous 64-col wave strips
    dim3 grid(IMG_W / (4 * STRIP), (IMG_H + CHUNK - 1) / CHUNK, NPLANES);
    ssim_main<<<grid, 256, 0, stream>>>(img1, img2, ws, gw);
    ssim_finalize<<<1, 1, 0, stream>>>(ws, out);
}